// Round 12
// baseline (1512.675 us; speedup 1.0000x reference)
//
#include <hip/hip_runtime.h>
#include <math.h>

#define D 256
#define PD 260  // padded LDS row: %4==0 (float4-aligned), %32==4 (bank shift)
#define TOK_B 16
#define TOK_T 8192
#define NTOK (TOK_B * TOK_T)
#define KSEL 100
#define ROWS 64   // k1: R13 optimum (64 tokens/block, 8 rows/thread, 2 blocks/CU)
#define K3T 4     // R18: k3 tokens/block 8 -> 4 (400 blocks, 2x TLP)

typedef unsigned long long ull;

// ---- scratch in device globals (d_ws untouched) ----
__device__ float g_txt[TOK_B * D];   // normalized text (f32, np semantics)
__device__ float g_obj[NTOK];        // obj sigmoid scores (f32)
__device__ int   g_sel[TOK_B * KSEL];

// ---------------------------------------------------------------------------
// numpy pairwise_sum emulation (serial form, used by K0).
// ---------------------------------------------------------------------------
template <typename F>
__device__ __forceinline__ float np_sum128_f(F f, int base) {
#pragma clang fp contract(off)
  float r0 = f(base + 0), r1 = f(base + 1), r2 = f(base + 2), r3 = f(base + 3);
  float r4 = f(base + 4), r5 = f(base + 5), r6 = f(base + 6), r7 = f(base + 7);
  for (int i = 8; i < 128; i += 8) {
    r0 += f(base + i + 0); r1 += f(base + i + 1);
    r2 += f(base + i + 2); r3 += f(base + i + 3);
    r4 += f(base + i + 4); r5 += f(base + i + 5);
    r6 += f(base + i + 6); r7 += f(base + i + 7);
  }
  return ((r0 + r1) + (r2 + r3)) + ((r4 + r5) + (r6 + r7));
}
template <typename F>
__device__ __forceinline__ float np_sum256_f(F f) {
#pragma clang fp contract(off)
  return np_sum128_f(f, 0) + np_sum128_f(f, 128);
}

// ---------------------------------------------------------------------------
// Parallel np pairwise sum: 8 lanes (j = lane&7) compute numpy accumulator
// r_j of both 128-halves in np order; combine tree via shfl_xor is
// bit-identical to np's ((r0+r1)+(r2+r3))+((r4+r5)+(r6+r7)).
// ---------------------------------------------------------------------------
template <typename F>
__device__ __forceinline__ float np_sum256_par8(F f, int j) {
#pragma clang fp contract(off)
  float s0 = f(j);
  for (int i = 1; i < 16; ++i) s0 += f(8 * i + j);
  float s1 = f(128 + j);
  for (int i = 1; i < 16; ++i) s1 += f(128 + 8 * i + j);
  s0 += __shfl_xor(s0, 1);
  s0 += __shfl_xor(s0, 2);
  s0 += __shfl_xor(s0, 4);
  s1 += __shfl_xor(s1, 1);
  s1 += __shfl_xor(s1, 2);
  s1 += __shfl_xor(s1, 4);
  return s0 + s1;
}

// scipy-style gelu: f32 divide by f32(sqrt2), f64 erf, f32 compose
__device__ __forceinline__ float np_geluf(float x) {
#pragma clang fp contract(off)
  const float t = x / 1.41421356237309504880f;
  const float e = (float)erf((double)t);
  return (0.5f * x) * (1.0f + e);
}
__device__ __forceinline__ float np_sigmoidf(float x) {
#pragma clang fp contract(off)
  return 1.0f / (1.0f + expf(-x));
}

// ---------------------------------------------------------------------------
// K0: txt = text_emb / sqrt(np.sum(text^2) + 1e-12), all f32 np semantics.
// ---------------------------------------------------------------------------
__global__ __launch_bounds__(256) void k0_txt(const float* __restrict__ text_emb) {
#pragma clang fp contract(off)
  const int b = blockIdx.x, tid = threadIdx.x;
  __shared__ float sSq[D];
  __shared__ float sTot;
  const float e = text_emb[b * D + tid];
  sSq[tid] = e * e;
  __syncthreads();
  if (tid == 0) {
    const float* p = sSq;
    sTot = np_sum256_f([&](int i) { return p[i]; });
  }
  __syncthreads();
  g_txt[b * D + tid] = e / sqrtf(sTot + 1e-12f);
}

// ---------------------------------------------------------------------------
// accumulating GEMM microkernel, R13-proven simple form (no pipelining, no
// sched pragmas, no LDS-W — direct L2 W reads + broadcast A from LDS).
// Session verdicts: sched_barrier pins regress (R11 spill, R16 fence tax),
// source ping-pong collapses (R9), LDS-W staging convoys (R14), 1-wave ILP
// exposes latency (R15). This form at 64 rows/block is the measured
// optimum: k1 = 1047-1053 us.
// acc[8][8] += S[r0..r0+7][:] @ W[:,c0..c0+7], strictly ascending k, one
// f32 fma chain per C element (bit-exact vs np).
// ---------------------------------------------------------------------------
__device__ __forceinline__ void gemm_acc8(const float (*__restrict__ S)[PD],
                                          const float* __restrict__ W, int r0,
                                          int c0, float acc[8][8]) {
  for (int k = 0; k < D; k += 4) {
    float ar[8][4];
#pragma unroll
    for (int i = 0; i < 8; ++i) {
      const float4 A = *(const float4*)&S[r0 + i][k];
      ar[i][0] = A.x; ar[i][1] = A.y; ar[i][2] = A.z; ar[i][3] = A.w;
    }
#pragma unroll
    for (int kk = 0; kk < 4; ++kk) {
      const float* wr = W + (size_t)(k + kk) * D + c0;
      float4 W0 = *(const float4*)wr;
      float4 W1 = *(const float4*)(wr + 4);
      const float wv[8] = {W0.x, W0.y, W0.z, W0.w, W1.x, W1.y, W1.z, W1.w};
#pragma unroll
      for (int i = 0; i < 8; ++i)
#pragma unroll
        for (int j = 0; j < 8; ++j)
          acc[i][j] = fmaf(ar[i][kk], wv[j], acc[i][j]);
    }
  }
}

// ---------------------------------------------------------------------------
// K1: obj scores for all tokens, bit-exact np-f32 semantics. FROZEN (R13).
// ---------------------------------------------------------------------------
__global__ __launch_bounds__(256, 2) void k1_obj(
    const float* __restrict__ vision, const float* __restrict__ fuse_w1,
    const float* __restrict__ fuse_b1, const float* __restrict__ fuse_w2,
    const float* __restrict__ fuse_b2, const float* __restrict__ obj_ln_g,
    const float* __restrict__ obj_ln_b, const float* __restrict__ obj_w1,
    const float* __restrict__ obj_b1, const float* __restrict__ obj_w2,
    const float* __restrict__ obj_b2) {
#pragma clang fp contract(off)
  const int tid = threadIdx.x;
  const int tr = tid >> 5, tc = tid & 31;
  const int r0 = tr << 3, c0 = tc << 3;   // 8 rows x 8 cols per thread
  const int blk = blockIdx.x;
  const int batch = blk >> 7;  // 128 blocks per batch (8192 tokens / 64)

  __shared__ float sA[ROWS][PD];  // vision -> gelu1 -> h -> oh -> q (in-place)
  __shared__ float sTxt[D];
  __shared__ float sMu[ROWS], sRstd[ROWS];

  // stage vision tile + txt row (pad-aware)
  {
    const float* src = vision + (size_t)blk * (ROWS * D);
#pragma unroll
    for (int i = 0; i < 16; ++i) {
      const int e = i * 1024 + tid * 4;
      const int row = e >> 8, col = e & 255;
      *(float4*)&sA[row][col] = *(const float4*)(src + e);
    }
    sTxt[tid] = g_txt[batch * D + tid];
  }
  __syncthreads();

  float acc[8][8];
#pragma unroll
  for (int i = 0; i < 8; ++i)
#pragma unroll
    for (int j = 0; j < 8; ++j) acc[i][j] = 0.0f;

  // GEMM1 part A: vision rows, k = 0..255 (ascending)
  gemm_acc8(sA, fuse_w1, r0, c0, acc);
  // GEMM1 part B: text rows, k = 256..511 (ascending); tv broadcast per k
  for (int k = 0; k < D; ++k) {
    const float tv = sTxt[k];
    const float* wr = fuse_w1 + (size_t)(D + k) * D + c0;
    float4 W0 = *(const float4*)wr;
    float4 W1 = *(const float4*)(wr + 4);
    const float wv[8] = {W0.x, W0.y, W0.z, W0.w, W1.x, W1.y, W1.z, W1.w};
#pragma unroll
    for (int i = 0; i < 8; ++i)
#pragma unroll
      for (int j = 0; j < 8; ++j) acc[i][j] = fmaf(tv, wv[j], acc[i][j]);
  }
  __syncthreads();  // all GEMM1 reads of sA (vision) complete
  // + b1, gelu -> sA (in place)
  {
#pragma unroll
    for (int j2 = 0; j2 < 8; ++j2) {
      const float b = fuse_b1[c0 + j2];
#pragma unroll
      for (int i = 0; i < 8; ++i)
        sA[r0 + i][c0 + j2] = np_geluf(acc[i][j2] + b);
    }
  }
  __syncthreads();

  // GEMM2: h = gelu1 @ w2 + b2 -> sA (in place)
#pragma unroll
  for (int i = 0; i < 8; ++i)
#pragma unroll
    for (int j = 0; j < 8; ++j) acc[i][j] = 0.0f;
  gemm_acc8(sA, fuse_w2, r0, c0, acc);
  __syncthreads();  // all GEMM2 reads of sA (gelu1) complete
  {
#pragma unroll
    for (int j2 = 0; j2 < 8; ++j2) {
      const float b = fuse_b2[c0 + j2];
#pragma unroll
      for (int i = 0; i < 8; ++i) sA[r0 + i][c0 + j2] = acc[i][j2] + b;
    }
  }
  __syncthreads();

  // LN stats, numpy pairwise, 8 lanes per row (exact np order); rows 0..63
  {
    const int j = tid & 7;
    for (int r = tid >> 3; r < ROWS; r += 32) {
      const float* hrow = &sA[r][0];
      const float mu =
          np_sum256_par8([&](int i) { return hrow[i]; }, j) / 256.0f;
      const float var = np_sum256_par8(
                            [&](int i) {
                              const float d = hrow[i] - mu;
                              return d * d;
                            },
                            j) /
                        256.0f;
      if (j == 0) {
        sMu[r] = mu;
        sRstd[r] = 1.0f / sqrtf(var + 1e-5f);
      }
    }
  }
  __syncthreads();

  // oh = ((h-mu)*rstd)*g + b -> sA (column-parallel, each thread owns col tid)
  {
    const float lg = obj_ln_g[tid], lb = obj_ln_b[tid];
    for (int r = 0; r < ROWS; ++r) {
      const float t = (sA[r][tid] - sMu[r]) * sRstd[r];
      sA[r][tid] = t * lg + lb;
    }
  }
  __syncthreads();

  // obj head GEMM: q = gelu(oh @ ow1 + ob1) -> sA (in place)
#pragma unroll
  for (int i = 0; i < 8; ++i)
#pragma unroll
    for (int j = 0; j < 8; ++j) acc[i][j] = 0.0f;
  gemm_acc8(sA, obj_w1, r0, c0, acc);
  __syncthreads();  // all obj-GEMM reads of sA (oh) complete
  {
#pragma unroll
    for (int j2 = 0; j2 < 8; ++j2) {
      const float b = obj_b1[c0 + j2];
#pragma unroll
      for (int i = 0; i < 8; ++i)
        sA[r0 + i][c0 + j2] = np_geluf(acc[i][j2] + b);
    }
  }
  __syncthreads();

  // logit = (q . ow2) + ob2, sequential ascending fma (np semantics).
  if (tid < ROWS) {
    const int row = tid;
    const float* q = &sA[row][0];
    float L = 0.0f;
    for (int k = 0; k < D; ++k) L = fmaf(q[k], obj_w2[k], L);
    L = L + obj_b2[0];
    g_obj[(size_t)blk * ROWS + row] = np_sigmoidf(L);
  }
}

// ---------------------------------------------------------------------------
// K2: per-batch top-100 via 128-group max tournament. Group g = elements
// {g + 128*j}; init reads are lane-consecutive (conflict-free). Per round:
// wave0 scans 128 group maxima, extracts winner (np tie semantics via packed
// key), zeroes it, recomputes only the winner's group. FROZEN.
// ---------------------------------------------------------------------------
__global__ __launch_bounds__(256) void k2_topk(float* __restrict__ out_scores) {
  const int b = blockIdx.x, tid = threadIdx.x;
  __shared__ ull sKey[TOK_T];
  __shared__ ull sGmax[128];
  __shared__ int sWin;
  for (int i = tid; i < TOK_T; i += 256) {
    const float s = g_obj[b * TOK_T + i];
    sKey[i] = ((ull)__float_as_uint(s) << 32) | (unsigned)(TOK_T - 1 - i);
  }
  __syncthreads();
  // init group maxima: thread t<128 scans its strided group (lane-consecutive)
  if (tid < 128) {
    ull m = 0ull;
    for (int j = 0; j < 64; ++j) {
      const ull v = sKey[tid + 128 * j];
      m = v > m ? v : m;
    }
    sGmax[tid] = m;
  }
  __syncthreads();
  for (int r = 0; r < KSEL; ++r) {
    if (tid < 64) {
      ull m = sGmax[tid];
      const ull o = sGmax[64 + tid];
      if (o > m) m = o;
#pragma unroll
      for (int off = 32; off > 0; off >>= 1) {
        const ull o2 = __shfl_down(m, off, 64);
        if (o2 > m) m = o2;
      }
      if (tid == 0) {
        const int idx = (TOK_T - 1) - (int)(unsigned)(m & 0xFFFFFFFFull);
        out_scores[b * KSEL + r] = __uint_as_float((unsigned)(m >> 32));
        g_sel[b * KSEL + r] = idx;
        sKey[idx] = 0ull;
        sWin = idx & 127;
      }
    }
    __syncthreads();
    if (tid < 64) {
      const int g = sWin;
      ull v = sKey[g + 128 * tid];
#pragma unroll
      for (int off = 32; off > 0; off >>= 1) {
        const ull o = __shfl_down(v, off, 64);
        if (o > v) v = o;
      }
      if (tid == 0) sGmax[g] = v;
    }
    __syncthreads();
  }
}

// ---------------------------------------------------------------------------
// K3: box head + text scores for the 1600 selected tokens, np-f32 semantics.
// R18: 4 tokens/block (was 8) -> 400 blocks, 1600 waves (~2/SIMD). k3 was
// ~1 wave/SIMD with fully-exposed per-k W-load latency (the R15 failure
// mode); doubling TLP pairwise-covers it. W traffic doubles but is tiny
// (~0.4 GB). Per-token arithmetic chains identical (tokens independent;
// each output column one ascending-k fma chain).
// ---------------------------------------------------------------------------
__global__ __launch_bounds__(256) void k3_box(
    const float* __restrict__ vision, const float* __restrict__ fuse_w1,
    const float* __restrict__ fuse_b1, const float* __restrict__ fuse_w2,
    const float* __restrict__ fuse_b2, const float* __restrict__ box_ln_g,
    const float* __restrict__ box_ln_b, const float* __restrict__ box_w1,
    const float* __restrict__ box_b1, const float* __restrict__ box_w2,
    const float* __restrict__ box_b2, float* __restrict__ out) {
#pragma clang fp contract(off)
  const int tid = threadIdx.x, c = tid;
  __shared__ float sV[K3T][PD];    // vision -> q(box)
  __shared__ float sG[K3T][PD];    // gelu1 -> bh
  __shared__ float sH[K3T][PD];    // h
  __shared__ float sTx[K3T][PD];   // per-token txt row
  __shared__ float sMu[K3T], sRstd[K3T];
  __shared__ int sIdx[K3T], sBat[K3T];
  if (tid < K3T) {
    const int e = blockIdx.x * K3T + tid;
    sBat[tid] = e / KSEL;
    sIdx[tid] = g_sel[e];
  }
  __syncthreads();
  {
    // wave u stages token u: 64 lanes x 4 floats = 256
    const int u = tid >> 6, col = (tid & 63) * 4;
    const float* src = vision + ((size_t)sBat[u] * TOK_T + sIdx[u]) * D + col;
    *(float4*)&sV[u][col] = *(const float4*)src;
    const float* tsrc = &g_txt[sBat[u] * D + col];
    *(float4*)&sTx[u][col] = *(const float4*)tsrc;
  }
  __syncthreads();

  float acc[K3T];
#pragma unroll
  for (int u = 0; u < K3T; ++u) acc[u] = 0.0f;
  // GEMM1: k = 0..255 vision, then k = 256..511 text (ascending)
  for (int k = 0; k < D; ++k) {
    const float w = fuse_w1[k * D + c];
#pragma unroll
    for (int u = 0; u < K3T; ++u) acc[u] = fmaf(sV[u][k], w, acc[u]);
  }
  for (int k = 0; k < D; ++k) {
    const float w = fuse_w1[(D + k) * D + c];
#pragma unroll
    for (int u = 0; u < K3T; ++u) acc[u] = fmaf(sTx[u][k], w, acc[u]);
  }
  {
    const float b = fuse_b1[c];
#pragma unroll
    for (int u = 0; u < K3T; ++u) sG[u][c] = np_geluf(acc[u] + b);
  }
  __syncthreads();

  // GEMM2 -> h
#pragma unroll
  for (int u = 0; u < K3T; ++u) acc[u] = 0.0f;
  for (int k = 0; k < D; ++k) {
    const float w = fuse_w2[k * D + c];
#pragma unroll
    for (int u = 0; u < K3T; ++u) acc[u] = fmaf(sG[u][k], w, acc[u]);
  }
  {
    const float b = fuse_b2[c];
#pragma unroll
    for (int u = 0; u < K3T; ++u) sH[u][c] = acc[u] + b;
  }
  __syncthreads();

  // per-token stats (np pairwise), 8 lanes per row; rows 0..3 on wave 0
  {
    const int u = tid >> 3, j = tid & 7;
    if (u < K3T) {
      const float* h = &sH[u][0];
      const float* tx = &sTx[u][0];
      const float mu = np_sum256_par8([&](int i) { return h[i]; }, j) / 256.0f;
      const float var = np_sum256_par8(
                            [&](int i) {
                              const float d = h[i] - mu;
                              return d * d;
                            },
                            j) /
                        256.0f;
      const float q2 = np_sum256_par8([&](int i) { return h[i] * h[i]; }, j);
      const float den = sqrtf(q2 + 1e-12f);
      const float ts =
          np_sum256_par8([&](int i) { return (h[i] / den) * tx[i]; }, j);
      if (j == 0) {
        sMu[u] = mu;
        sRstd[u] = 1.0f / sqrtf(var + 1e-5f);
        out[8000 + blockIdx.x * K3T + u] = ts;
      }
    }
  }
  __syncthreads();

  // bh -> sG
  {
    const float lg = box_ln_g[c], lb = box_ln_b[c];
#pragma unroll
    for (int u = 0; u < K3T; ++u) {
      const float t = (sH[u][c] - sMu[u]) * sRstd[u];
      sG[u][c] = t * lg + lb;
    }
  }
  __syncthreads();

  // box GEMM: q = gelu(bh @ bw1 + bb1) -> sV
#pragma unroll
  for (int u = 0; u < K3T; ++u) acc[u] = 0.0f;
  for (int k = 0; k < D; ++k) {
    const float w = box_w1[k * D + c];
#pragma unroll
    for (int u = 0; u < K3T; ++u) acc[u] = fmaf(sG[u][k], w, acc[u]);
  }
  {
    const float b = box_b1[c];
#pragma unroll
    for (int u = 0; u < K3T; ++u) sV[u][c] = np_geluf(acc[u] + b);
  }
  __syncthreads();

  // logits: sequential ascending fma per (token, j), then + b2, sigmoid
  if (tid < K3T * 4) {
    const int u = tid >> 2, j = tid & 3;
    const float* q = &sV[u][0];
    float L = 0.0f;
    for (int k = 0; k < D; ++k) L = fmaf(q[k], box_w2[k * 4 + j], L);
    L = L + box_b2[j];
    out[(blockIdx.x * K3T + u) * 4 + j] = np_sigmoidf(L);
  }
}

extern "C" void kernel_launch(void* const* d_in, const int* in_sizes, int n_in,
                              void* d_out, int out_size, void* d_ws,
                              size_t ws_size, hipStream_t stream) {
  const float* vision   = (const float*)d_in[0];
  const float* text_emb = (const float*)d_in[1];
  const float* fuse_w1  = (const float*)d_in[2];
  const float* fuse_b1  = (const float*)d_in[3];
  const float* fuse_w2  = (const float*)d_in[4];
  const float* fuse_b2  = (const float*)d_in[5];
  const float* box_ln_g = (const float*)d_in[6];
  const float* box_ln_b = (const float*)d_in[7];
  const float* box_w1   = (const float*)d_in[8];
  const float* box_b1   = (const float*)d_in[9];
  const float* box_w2   = (const float*)d_in[10];
  const float* box_b2   = (const float*)d_in[11];
  const float* obj_ln_g = (const float*)d_in[12];
  const float* obj_ln_b = (const float*)d_in[13];
  const float* obj_w1   = (const float*)d_in[14];
  const float* obj_b1   = (const float*)d_in[15];
  const float* obj_w2   = (const float*)d_in[16];
  const float* obj_b2   = (const float*)d_in[17];
  float* out = (float*)d_out;

  k0_txt<<<TOK_B, 256, 0, stream>>>(text_emb);
  k1_obj<<<NTOK / ROWS, 256, 0, stream>>>(
      vision, fuse_w1, fuse_b1, fuse_w2, fuse_b2, obj_ln_g, obj_ln_b, obj_w1,
      obj_b1, obj_w2, obj_b2);
  k2_topk<<<TOK_B, 256, 0, stream>>>(out + 6400);
  k3_box<<<(TOK_B * KSEL) / K3T, 256, 0, stream>>>(
      vision, fuse_w1, fuse_b1, fuse_w2, fuse_b2, box_ln_g, box_ln_b, box_w1,
      box_b1, box_w2, box_b2, out);
}

// Round 13
// 1247.949 us; speedup vs baseline: 1.2121x; 1.2121x over previous
//
#include <hip/hip_runtime.h>
#include <math.h>

#define D 256
#define PD 260  // padded LDS row: %4==0 (float4-aligned), %32==4 (bank shift)
#define TOK_B 16
#define TOK_T 8192
#define NTOK (TOK_B * TOK_T)
#define KSEL 100
#define ROWS 64   // k1: R13 optimum (64 tokens/block, 8 rows/thread, 2 blocks/CU)
#define K3T 4     // R18: k3 tokens/block 8 -> 4 (400 blocks, 2x TLP) — confirmed via k1-normalized A/B

typedef unsigned long long ull;

// ---- scratch in device globals (d_ws untouched) ----
__device__ float g_txt[TOK_B * D];   // normalized text (f32, np semantics)
__device__ float g_obj[NTOK];        // obj sigmoid scores (f32)
__device__ int   g_sel[TOK_B * KSEL];

// ---------------------------------------------------------------------------
// numpy pairwise_sum emulation (serial form, used by K0).
// ---------------------------------------------------------------------------
template <typename F>
__device__ __forceinline__ float np_sum128_f(F f, int base) {
#pragma clang fp contract(off)
  float r0 = f(base + 0), r1 = f(base + 1), r2 = f(base + 2), r3 = f(base + 3);
  float r4 = f(base + 4), r5 = f(base + 5), r6 = f(base + 6), r7 = f(base + 7);
  for (int i = 8; i < 128; i += 8) {
    r0 += f(base + i + 0); r1 += f(base + i + 1);
    r2 += f(base + i + 2); r3 += f(base + i + 3);
    r4 += f(base + i + 4); r5 += f(base + i + 5);
    r6 += f(base + i + 6); r7 += f(base + i + 7);
  }
  return ((r0 + r1) + (r2 + r3)) + ((r4 + r5) + (r6 + r7));
}
template <typename F>
__device__ __forceinline__ float np_sum256_f(F f) {
#pragma clang fp contract(off)
  return np_sum128_f(f, 0) + np_sum128_f(f, 128);
}

// ---------------------------------------------------------------------------
// Parallel np pairwise sum: 8 lanes (j = lane&7) compute numpy accumulator
// r_j of both 128-halves in np order; combine tree via shfl_xor is
// bit-identical to np's ((r0+r1)+(r2+r3))+((r4+r5)+(r6+r7)).
// ---------------------------------------------------------------------------
template <typename F>
__device__ __forceinline__ float np_sum256_par8(F f, int j) {
#pragma clang fp contract(off)
  float s0 = f(j);
  for (int i = 1; i < 16; ++i) s0 += f(8 * i + j);
  float s1 = f(128 + j);
  for (int i = 1; i < 16; ++i) s1 += f(128 + 8 * i + j);
  s0 += __shfl_xor(s0, 1);
  s0 += __shfl_xor(s0, 2);
  s0 += __shfl_xor(s0, 4);
  s1 += __shfl_xor(s1, 1);
  s1 += __shfl_xor(s1, 2);
  s1 += __shfl_xor(s1, 4);
  return s0 + s1;
}

// scipy-style gelu: f32 divide by f32(sqrt2), f64 erf, f32 compose
__device__ __forceinline__ float np_geluf(float x) {
#pragma clang fp contract(off)
  const float t = x / 1.41421356237309504880f;
  const float e = (float)erf((double)t);
  return (0.5f * x) * (1.0f + e);
}
__device__ __forceinline__ float np_sigmoidf(float x) {
#pragma clang fp contract(off)
  return 1.0f / (1.0f + expf(-x));
}

// ---------------------------------------------------------------------------
// K0: txt = text_emb / sqrt(np.sum(text^2) + 1e-12), all f32 np semantics.
// ---------------------------------------------------------------------------
__global__ __launch_bounds__(256) void k0_txt(const float* __restrict__ text_emb) {
#pragma clang fp contract(off)
  const int b = blockIdx.x, tid = threadIdx.x;
  __shared__ float sSq[D];
  __shared__ float sTot;
  const float e = text_emb[b * D + tid];
  sSq[tid] = e * e;
  __syncthreads();
  if (tid == 0) {
    const float* p = sSq;
    sTot = np_sum256_f([&](int i) { return p[i]; });
  }
  __syncthreads();
  g_txt[b * D + tid] = e / sqrtf(sTot + 1e-12f);
}

// ---------------------------------------------------------------------------
// accumulating GEMM microkernel, R13-proven simple form (no pipelining, no
// sched pragmas, no LDS-W — direct L2 W reads + broadcast A from LDS).
// Session verdicts: sched_barrier pins regress (R11 spill, R16 fence tax),
// source ping-pong collapses (R9), LDS-W staging convoys (R14), 1-wave ILP
// exposes latency (R15). This form at 64 rows/block is the measured
// optimum: k1 = 1047-1053 us (fast container).
// acc[8][8] += S[r0..r0+7][:] @ W[:,c0..c0+7], strictly ascending k, one
// f32 fma chain per C element (bit-exact vs np).
// ---------------------------------------------------------------------------
__device__ __forceinline__ void gemm_acc8(const float (*__restrict__ S)[PD],
                                          const float* __restrict__ W, int r0,
                                          int c0, float acc[8][8]) {
  for (int k = 0; k < D; k += 4) {
    float ar[8][4];
#pragma unroll
    for (int i = 0; i < 8; ++i) {
      const float4 A = *(const float4*)&S[r0 + i][k];
      ar[i][0] = A.x; ar[i][1] = A.y; ar[i][2] = A.z; ar[i][3] = A.w;
    }
#pragma unroll
    for (int kk = 0; kk < 4; ++kk) {
      const float* wr = W + (size_t)(k + kk) * D + c0;
      float4 W0 = *(const float4*)wr;
      float4 W1 = *(const float4*)(wr + 4);
      const float wv[8] = {W0.x, W0.y, W0.z, W0.w, W1.x, W1.y, W1.z, W1.w};
#pragma unroll
      for (int i = 0; i < 8; ++i)
#pragma unroll
        for (int j = 0; j < 8; ++j)
          acc[i][j] = fmaf(ar[i][kk], wv[j], acc[i][j]);
    }
  }
}

// ---------------------------------------------------------------------------
// K1: obj scores for all tokens, bit-exact np-f32 semantics. FROZEN (R13).
// ---------------------------------------------------------------------------
__global__ __launch_bounds__(256, 2) void k1_obj(
    const float* __restrict__ vision, const float* __restrict__ fuse_w1,
    const float* __restrict__ fuse_b1, const float* __restrict__ fuse_w2,
    const float* __restrict__ fuse_b2, const float* __restrict__ obj_ln_g,
    const float* __restrict__ obj_ln_b, const float* __restrict__ obj_w1,
    const float* __restrict__ obj_b1, const float* __restrict__ obj_w2,
    const float* __restrict__ obj_b2) {
#pragma clang fp contract(off)
  const int tid = threadIdx.x;
  const int tr = tid >> 5, tc = tid & 31;
  const int r0 = tr << 3, c0 = tc << 3;   // 8 rows x 8 cols per thread
  const int blk = blockIdx.x;
  const int batch = blk >> 7;  // 128 blocks per batch (8192 tokens / 64)

  __shared__ float sA[ROWS][PD];  // vision -> gelu1 -> h -> oh -> q (in-place)
  __shared__ float sTxt[D];
  __shared__ float sMu[ROWS], sRstd[ROWS];

  // stage vision tile + txt row (pad-aware)
  {
    const float* src = vision + (size_t)blk * (ROWS * D);
#pragma unroll
    for (int i = 0; i < 16; ++i) {
      const int e = i * 1024 + tid * 4;
      const int row = e >> 8, col = e & 255;
      *(float4*)&sA[row][col] = *(const float4*)(src + e);
    }
    sTxt[tid] = g_txt[batch * D + tid];
  }
  __syncthreads();

  float acc[8][8];
#pragma unroll
  for (int i = 0; i < 8; ++i)
#pragma unroll
    for (int j = 0; j < 8; ++j) acc[i][j] = 0.0f;

  // GEMM1 part A: vision rows, k = 0..255 (ascending)
  gemm_acc8(sA, fuse_w1, r0, c0, acc);
  // GEMM1 part B: text rows, k = 256..511 (ascending); tv broadcast per k
  for (int k = 0; k < D; ++k) {
    const float tv = sTxt[k];
    const float* wr = fuse_w1 + (size_t)(D + k) * D + c0;
    float4 W0 = *(const float4*)wr;
    float4 W1 = *(const float4*)(wr + 4);
    const float wv[8] = {W0.x, W0.y, W0.z, W0.w, W1.x, W1.y, W1.z, W1.w};
#pragma unroll
    for (int i = 0; i < 8; ++i)
#pragma unroll
      for (int j = 0; j < 8; ++j) acc[i][j] = fmaf(tv, wv[j], acc[i][j]);
  }
  __syncthreads();  // all GEMM1 reads of sA (vision) complete
  // + b1, gelu -> sA (in place)
  {
#pragma unroll
    for (int j2 = 0; j2 < 8; ++j2) {
      const float b = fuse_b1[c0 + j2];
#pragma unroll
      for (int i = 0; i < 8; ++i)
        sA[r0 + i][c0 + j2] = np_geluf(acc[i][j2] + b);
    }
  }
  __syncthreads();

  // GEMM2: h = gelu1 @ w2 + b2 -> sA (in place)
#pragma unroll
  for (int i = 0; i < 8; ++i)
#pragma unroll
    for (int j = 0; j < 8; ++j) acc[i][j] = 0.0f;
  gemm_acc8(sA, fuse_w2, r0, c0, acc);
  __syncthreads();  // all GEMM2 reads of sA (gelu1) complete
  {
#pragma unroll
    for (int j2 = 0; j2 < 8; ++j2) {
      const float b = fuse_b2[c0 + j2];
#pragma unroll
      for (int i = 0; i < 8; ++i) sA[r0 + i][c0 + j2] = acc[i][j2] + b;
    }
  }
  __syncthreads();

  // LN stats, numpy pairwise, 8 lanes per row (exact np order); rows 0..63
  {
    const int j = tid & 7;
    for (int r = tid >> 3; r < ROWS; r += 32) {
      const float* hrow = &sA[r][0];
      const float mu =
          np_sum256_par8([&](int i) { return hrow[i]; }, j) / 256.0f;
      const float var = np_sum256_par8(
                            [&](int i) {
                              const float d = hrow[i] - mu;
                              return d * d;
                            },
                            j) /
                        256.0f;
      if (j == 0) {
        sMu[r] = mu;
        sRstd[r] = 1.0f / sqrtf(var + 1e-5f);
      }
    }
  }
  __syncthreads();

  // oh = ((h-mu)*rstd)*g + b -> sA (column-parallel, each thread owns col tid)
  {
    const float lg = obj_ln_g[tid], lb = obj_ln_b[tid];
    for (int r = 0; r < ROWS; ++r) {
      const float t = (sA[r][tid] - sMu[r]) * sRstd[r];
      sA[r][tid] = t * lg + lb;
    }
  }
  __syncthreads();

  // obj head GEMM: q = gelu(oh @ ow1 + ob1) -> sA (in place)
#pragma unroll
  for (int i = 0; i < 8; ++i)
#pragma unroll
    for (int j = 0; j < 8; ++j) acc[i][j] = 0.0f;
  gemm_acc8(sA, obj_w1, r0, c0, acc);
  __syncthreads();  // all obj-GEMM reads of sA (oh) complete
  {
#pragma unroll
    for (int j2 = 0; j2 < 8; ++j2) {
      const float b = obj_b1[c0 + j2];
#pragma unroll
      for (int i = 0; i < 8; ++i)
        sA[r0 + i][c0 + j2] = np_geluf(acc[i][j2] + b);
    }
  }
  __syncthreads();

  // logit = (q . ow2) + ob2, sequential ascending fma (np semantics).
  if (tid < ROWS) {
    const int row = tid;
    const float* q = &sA[row][0];
    float L = 0.0f;
    for (int k = 0; k < D; ++k) L = fmaf(q[k], obj_w2[k], L);
    L = L + obj_b2[0];
    g_obj[(size_t)blk * ROWS + row] = np_sigmoidf(L);
  }
}

// ---------------------------------------------------------------------------
// K2: per-batch top-100 via 128-group max tournament. Group g = elements
// {g + 128*j}; init reads are lane-consecutive (conflict-free). Per round:
// wave0 scans 128 group maxima, extracts winner (np tie semantics via packed
// key), zeroes it, recomputes only the winner's group. FROZEN.
// ---------------------------------------------------------------------------
__global__ __launch_bounds__(256) void k2_topk(float* __restrict__ out_scores) {
  const int b = blockIdx.x, tid = threadIdx.x;
  __shared__ ull sKey[TOK_T];
  __shared__ ull sGmax[128];
  __shared__ int sWin;
  for (int i = tid; i < TOK_T; i += 256) {
    const float s = g_obj[b * TOK_T + i];
    sKey[i] = ((ull)__float_as_uint(s) << 32) | (unsigned)(TOK_T - 1 - i);
  }
  __syncthreads();
  // init group maxima: thread t<128 scans its strided group (lane-consecutive)
  if (tid < 128) {
    ull m = 0ull;
    for (int j = 0; j < 64; ++j) {
      const ull v = sKey[tid + 128 * j];
      m = v > m ? v : m;
    }
    sGmax[tid] = m;
  }
  __syncthreads();
  for (int r = 0; r < KSEL; ++r) {
    if (tid < 64) {
      ull m = sGmax[tid];
      const ull o = sGmax[64 + tid];
      if (o > m) m = o;
#pragma unroll
      for (int off = 32; off > 0; off >>= 1) {
        const ull o2 = __shfl_down(m, off, 64);
        if (o2 > m) m = o2;
      }
      if (tid == 0) {
        const int idx = (TOK_T - 1) - (int)(unsigned)(m & 0xFFFFFFFFull);
        out_scores[b * KSEL + r] = __uint_as_float((unsigned)(m >> 32));
        g_sel[b * KSEL + r] = idx;
        sKey[idx] = 0ull;
        sWin = idx & 127;
      }
    }
    __syncthreads();
    if (tid < 64) {
      const int g = sWin;
      ull v = sKey[g + 128 * tid];
#pragma unroll
      for (int off = 32; off > 0; off >>= 1) {
        const ull o = __shfl_down(v, off, 64);
        if (o > v) v = o;
      }
      if (tid == 0) sGmax[g] = v;
    }
    __syncthreads();
  }
}

// ---------------------------------------------------------------------------
// K3: box head + text scores for the 1600 selected tokens, np-f32 semantics.
// R18: 4 tokens/block -> 400 blocks, 1600 waves (~2/SIMD); k1-normalized
// A/B (R12) confirms ~-35 us vs 8 tokens/block. Per-token arithmetic chains
// identical (tokens independent; each output column one ascending-k chain).
// ---------------------------------------------------------------------------
__global__ __launch_bounds__(256) void k3_box(
    const float* __restrict__ vision, const float* __restrict__ fuse_w1,
    const float* __restrict__ fuse_b1, const float* __restrict__ fuse_w2,
    const float* __restrict__ fuse_b2, const float* __restrict__ box_ln_g,
    const float* __restrict__ box_ln_b, const float* __restrict__ box_w1,
    const float* __restrict__ box_b1, const float* __restrict__ box_w2,
    const float* __restrict__ box_b2, float* __restrict__ out) {
#pragma clang fp contract(off)
  const int tid = threadIdx.x, c = tid;
  __shared__ float sV[K3T][PD];    // vision -> q(box)
  __shared__ float sG[K3T][PD];    // gelu1 -> bh
  __shared__ float sH[K3T][PD];    // h
  __shared__ float sTx[K3T][PD];   // per-token txt row
  __shared__ float sMu[K3T], sRstd[K3T];
  __shared__ int sIdx[K3T], sBat[K3T];
  if (tid < K3T) {
    const int e = blockIdx.x * K3T + tid;
    sBat[tid] = e / KSEL;
    sIdx[tid] = g_sel[e];
  }
  __syncthreads();
  {
    // wave u stages token u: 64 lanes x 4 floats = 256
    const int u = tid >> 6, col = (tid & 63) * 4;
    const float* src = vision + ((size_t)sBat[u] * TOK_T + sIdx[u]) * D + col;
    *(float4*)&sV[u][col] = *(const float4*)src;
    const float* tsrc = &g_txt[sBat[u] * D + col];
    *(float4*)&sTx[u][col] = *(const float4*)tsrc;
  }
  __syncthreads();

  float acc[K3T];
#pragma unroll
  for (int u = 0; u < K3T; ++u) acc[u] = 0.0f;
  // GEMM1: k = 0..255 vision, then k = 256..511 text (ascending)
  for (int k = 0; k < D; ++k) {
    const float w = fuse_w1[k * D + c];
#pragma unroll
    for (int u = 0; u < K3T; ++u) acc[u] = fmaf(sV[u][k], w, acc[u]);
  }
  for (int k = 0; k < D; ++k) {
    const float w = fuse_w1[(D + k) * D + c];
#pragma unroll
    for (int u = 0; u < K3T; ++u) acc[u] = fmaf(sTx[u][k], w, acc[u]);
  }
  {
    const float b = fuse_b1[c];
#pragma unroll
    for (int u = 0; u < K3T; ++u) sG[u][c] = np_geluf(acc[u] + b);
  }
  __syncthreads();

  // GEMM2 -> h
#pragma unroll
  for (int u = 0; u < K3T; ++u) acc[u] = 0.0f;
  for (int k = 0; k < D; ++k) {
    const float w = fuse_w2[k * D + c];
#pragma unroll
    for (int u = 0; u < K3T; ++u) acc[u] = fmaf(sG[u][k], w, acc[u]);
  }
  {
    const float b = fuse_b2[c];
#pragma unroll
    for (int u = 0; u < K3T; ++u) sH[u][c] = acc[u] + b;
  }
  __syncthreads();

  // per-token stats (np pairwise), 8 lanes per row; rows 0..3 on wave 0
  {
    const int u = tid >> 3, j = tid & 7;
    if (u < K3T) {
      const float* h = &sH[u][0];
      const float* tx = &sTx[u][0];
      const float mu = np_sum256_par8([&](int i) { return h[i]; }, j) / 256.0f;
      const float var = np_sum256_par8(
                            [&](int i) {
                              const float d = h[i] - mu;
                              return d * d;
                            },
                            j) /
                        256.0f;
      const float q2 = np_sum256_par8([&](int i) { return h[i] * h[i]; }, j);
      const float den = sqrtf(q2 + 1e-12f);
      const float ts =
          np_sum256_par8([&](int i) { return (h[i] / den) * tx[i]; }, j);
      if (j == 0) {
        sMu[u] = mu;
        sRstd[u] = 1.0f / sqrtf(var + 1e-5f);
        out[8000 + blockIdx.x * K3T + u] = ts;
      }
    }
  }
  __syncthreads();

  // bh -> sG
  {
    const float lg = box_ln_g[c], lb = box_ln_b[c];
#pragma unroll
    for (int u = 0; u < K3T; ++u) {
      const float t = (sH[u][c] - sMu[u]) * sRstd[u];
      sG[u][c] = t * lg + lb;
    }
  }
  __syncthreads();

  // box GEMM: q = gelu(bh @ bw1 + bb1) -> sV
#pragma unroll
  for (int u = 0; u < K3T; ++u) acc[u] = 0.0f;
  for (int k = 0; k < D; ++k) {
    const float w = box_w1[k * D + c];
#pragma unroll
    for (int u = 0; u < K3T; ++u) acc[u] = fmaf(sG[u][k], w, acc[u]);
  }
  {
    const float b = box_b1[c];
#pragma unroll
    for (int u = 0; u < K3T; ++u) sV[u][c] = np_geluf(acc[u] + b);
  }
  __syncthreads();

  // logits: sequential ascending fma per (token, j), then + b2, sigmoid
  if (tid < K3T * 4) {
    const int u = tid >> 2, j = tid & 3;
    const float* q = &sV[u][0];
    float L = 0.0f;
    for (int k = 0; k < D; ++k) L = fmaf(q[k], box_w2[k * 4 + j], L);
    L = L + box_b2[j];
    out[(blockIdx.x * K3T + u) * 4 + j] = np_sigmoidf(L);
  }
}

extern "C" void kernel_launch(void* const* d_in, const int* in_sizes, int n_in,
                              void* d_out, int out_size, void* d_ws,
                              size_t ws_size, hipStream_t stream) {
  const float* vision   = (const float*)d_in[0];
  const float* text_emb = (const float*)d_in[1];
  const float* fuse_w1  = (const float*)d_in[2];
  const float* fuse_b1  = (const float*)d_in[3];
  const float* fuse_w2  = (const float*)d_in[4];
  const float* fuse_b2  = (const float*)d_in[5];
  const float* box_ln_g = (const float*)d_in[6];
  const float* box_ln_b = (const float*)d_in[7];
  const float* box_w1   = (const float*)d_in[8];
  const float* box_b1   = (const float*)d_in[9];
  const float* box_w2   = (const float*)d_in[10];
  const float* box_b2   = (const float*)d_in[11];
  const float* obj_ln_g = (const float*)d_in[12];
  const float* obj_ln_b = (const float*)d_in[13];
  const float* obj_w1   = (const float*)d_in[14];
  const float* obj_b1   = (const float*)d_in[15];
  const float* obj_w2   = (const float*)d_in[16];
  const float* obj_b2   = (const float*)d_in[17];
  float* out = (float*)d_out;

  k0_txt<<<TOK_B, 256, 0, stream>>>(text_emb);
  k1_obj<<<NTOK / ROWS, 256, 0, stream>>>(
      vision, fuse_w1, fuse_b1, fuse_w2, fuse_b2, obj_ln_g, obj_ln_b, obj_w1,
      obj_b1, obj_w2, obj_b2);
  k2_topk<<<TOK_B, 256, 0, stream>>>(out + 6400);
  k3_box<<<(TOK_B * KSEL) / K3T, 256, 0, stream>>>(
      vision, fuse_w1, fuse_b1, fuse_w2, fuse_b2, box_ln_g, box_ln_b, box_w1,
      box_b1, box_w2, box_b2, out);
}